// Round 16
// baseline (384.318 us; speedup 1.0000x reference)
//
#include <hip/hip_runtime.h>
#include <hip/hip_bf16.h>

typedef __attribute__((ext_vector_type(8))) __bf16 bf16x8;
typedef __attribute__((ext_vector_type(4))) __bf16 bf16x4;
typedef __attribute__((ext_vector_type(4))) float f32x4;

#define MFMA16(a, b, c) __builtin_amdgcn_mfma_f32_16x16x32_bf16((a), (b), (c), 0, 0, 0)

// ---------------------------------------------------------------------------
// K0: cast f32 -> bf16 (X3 and W4).
// ---------------------------------------------------------------------------
__global__ __launch_bounds__(256) void cast_kernel(
    const float* __restrict__ xq, const float* __restrict__ xk,
    const float* __restrict__ xv, const float* __restrict__ Wq,
    const float* __restrict__ Wk, const float* __restrict__ Wv,
    const float* __restrict__ Wo, __bf16* __restrict__ oxq,
    __bf16* __restrict__ oxk, __bf16* __restrict__ oxv,
    __bf16* __restrict__ owq, __bf16* __restrict__ owk,
    __bf16* __restrict__ owv, __bf16* __restrict__ owo) {
  int bid = blockIdx.x;
  const float* src;
  __bf16* dst;
  int base;
  if (bid < 3072) { src = xq; dst = oxq; base = bid; }
  else if (bid < 6144) { src = xk; dst = oxk; base = bid - 3072; }
  else if (bid < 9216) { src = xv; dst = oxv; base = bid - 6144; }
  else if (bid < 9792) { src = Wq; dst = owq; base = bid - 9216; }
  else if (bid < 10368) { src = Wk; dst = owk; base = bid - 9792; }
  else if (bid < 10944) { src = Wv; dst = owv; base = bid - 10368; }
  else { src = Wo; dst = owo; base = bid - 10944; }
  int idx = base * 256 + threadIdx.x;
  f32x4 v = *(const f32x4*)&src[idx * 4];
  bf16x4 o;
  o[0] = (__bf16)v[0]; o[1] = (__bf16)v[1]; o[2] = (__bf16)v[2]; o[3] = (__bf16)v[3];
  *(bf16x4*)&dst[idx * 4] = o;
}

// ---------------------------------------------------------------------------
// K1: QKV projection, bf16 inputs, 1 wave per 64x64 tile, grid 2304.
// p<2: out[(b*12+h)*2048+pos][hd];  p==2: out[(b*12+h)*64+hd][pos] (v^T)
// ---------------------------------------------------------------------------
__global__ __launch_bounds__(64) void qkv_kernel(
    const __bf16* __restrict__ xq, const __bf16* __restrict__ xk,
    const __bf16* __restrict__ xv, const __bf16* __restrict__ wq,
    const __bf16* __restrict__ wk, const __bf16* __restrict__ wvp,
    const float* __restrict__ bq, const float* __restrict__ bk,
    const float* __restrict__ bv, __bf16* __restrict__ qo,
    __bf16* __restrict__ ko, __bf16* __restrict__ vo) {
  int wg = blockIdx.x;
  int p = wg / 768;
  int wgi = wg - p * 768;
  const __bf16* X = (p == 0) ? xq : (p == 1) ? xk : xv;
  const __bf16* W = (p == 0) ? wq : (p == 1) ? wk : wvp;
  const float* bias = (p == 0) ? bq : (p == 1) ? bk : bv;
  __bf16* out = (p == 0) ? qo : (p == 1) ? ko : vo;
  float scale = (p == 0) ? 0.125f : 1.0f;
  int vmode = (p == 2);

  int lane = threadIdx.x & 63;
  int lr = lane & 15, kg = lane >> 4;
  int mt = wgi / 12, nt = wgi - mt * 12;
  int m0 = mt * 64, n0 = nt * 64;
  f32x4 acc[4][4];
#pragma unroll
  for (int i = 0; i < 4; i++)
#pragma unroll
    for (int j = 0; j < 4; j++) acc[i][j] = (f32x4){0.f, 0.f, 0.f, 0.f};

  for (int k0 = 0; k0 < 768; k0 += 32) {
    bf16x8 af[4], bw[4];
#pragma unroll
    for (int i = 0; i < 4; i++) {
      af[i] = *(const bf16x8*)(X + (size_t)(m0 + i * 16 + lr) * 768 + k0 + kg * 8);
      bw[i] = *(const bf16x8*)(W + (size_t)(n0 + i * 16 + lr) * 768 + k0 + kg * 8);
    }
#pragma unroll
    for (int i = 0; i < 4; i++)
#pragma unroll
      for (int j = 0; j < 4; j++) acc[i][j] = MFMA16(af[i], bw[j], acc[i][j]);
  }

  int h = nt;
#pragma unroll
  for (int i = 0; i < 4; i++)
#pragma unroll
    for (int j = 0; j < 4; j++)
#pragma unroll
      for (int r = 0; r < 4; r++) {
        int m = m0 + i * 16 + kg * 4 + r;
        int hd = j * 16 + lr;
        float v = (acc[i][j][r] + bias[n0 + hd]) * scale;
        int b = m >> 11, pos = m & 2047;
        size_t idx;
        if (!vmode)
          idx = ((size_t)(b * 12 + h) * 2048 + pos) * 64 + hd;
        else
          idx = ((size_t)(b * 12 + h) * 64 + hd) * 2048 + pos;
        out[idx] = (__bf16)v;
      }
}

// ---------------------------------------------------------------------------
// K2: fused attention (r15 structure + XCD-pinned bh mapping).
// Per (b, h, 16-row q-tile). 1024 threads = 16 waves. LDS ~74KB -> 2 blk/CU.
// Grid map: xcd = wg&7 (round-robin dispatch), each XCD owns 3 bh values ->
// per-XCD K/V working set 2.3MB < 4MB L2 -> Phase A/C loads are L2 hits.
// rpos nontemporal loads; wout nontemporal stores (zero-reuse streams).
// ---------------------------------------------------------------------------
__global__ __launch_bounds__(1024, 8) void attn_kernel(
    const __bf16* __restrict__ qw, const __bf16* __restrict__ kw,
    const __bf16* __restrict__ vT, const int* __restrict__ kpm,
    const float* __restrict__ amask, const float* __restrict__ rpos,
    float* __restrict__ wout, float* __restrict__ attn_pre) {
  __shared__ __align__(16) unsigned char smem[16 * 2056 * 2];  // sc / pl union
  __shared__ __align__(16) float bias[2048];
  __shared__ float invA[16];
  auto sc = (__bf16(*)[2056])smem;
  auto pl = (float(*)[4][16][16])smem;  // 16KB, overlaid after all sc reads

  int wg = blockIdx.x;
  int xcd = wg & 7;          // dispatcher round-robins blocks across XCDs
  int idx = wg >> 3;         // 0..383
  int bh = xcd * 3 + idx / 128;  // 3 bh per XCD -> K/V pinned in its L2
  int qt = idx & 127;
  int b = bh / 12, h = bh - b * 12;
  int t0 = qt * 16;
  int wv = threadIdx.x >> 6, lane = threadIdx.x & 63;
  int lr = lane & 15, kg = lane >> 4;

  const __bf16* qp = qw + (size_t)bh * 2048 * 64;
  const __bf16* kp = kw + (size_t)bh * 2048 * 64;
  const __bf16* vp = vT + (size_t)bh * 64 * 2048;

  int m = wv;        // phase-B row owned by this wave
  int t = t0 + m;
  const float* rp = rpos + ((size_t)bh * 2048 + t) * 2048;
  const float* am = amask + (size_t)t * 2048;

  // kpm -> additive bias in LDS (depends only on b)
  {
    int i0 = threadIdx.x * 2;
    int2 kk = *(const int2*)&kpm[b * 2048 + i0];
    bias[i0] = kk.x ? -__builtin_inff() : 0.0f;
    bias[i0 + 1] = kk.y ? -__builtin_inff() : 0.0f;
  }

  // rpos prefetch (nontemporal): first 4 f32x4, hidden under Phase A.
  f32x4 rb[4];
#pragma unroll
  for (int i = 0; i < 4; i++)
    rb[i] = __builtin_nontemporal_load((const f32x4*)&rp[lane * 4 + 256 * i]);

  // Phase A: scores [16][2048] -> bf16 LDS; 2-deep K prefetch pipeline.
  bf16x8 a0 = *(const bf16x8*)(qp + (size_t)(t0 + lr) * 64 + kg * 8);
  bf16x8 a1 = *(const bf16x8*)(qp + (size_t)(t0 + lr) * 64 + 32 + kg * 8);
  {
    int nt = wv;
    const __bf16* kb = kp + (size_t)(nt * 16 + lr) * 64 + kg * 8;
    bf16x8 b0 = *(const bf16x8*)kb;
    bf16x8 b1 = *(const bf16x8*)(kb + 32);
#pragma unroll
    for (int it = 0; it < 8; it++) {
      bf16x8 c0 = b0, c1 = b1;
      if (it < 7) {
        const __bf16* kn = kp + (size_t)((nt + 16) * 16 + lr) * 64 + kg * 8;
        b0 = *(const bf16x8*)kn;
        b1 = *(const bf16x8*)(kn + 32);
      }
      __builtin_amdgcn_sched_barrier(0);  // pin prefetch issue before MFMA
      f32x4 c = (f32x4){0.f, 0.f, 0.f, 0.f};
      c = MFMA16(a0, c0, c);
      c = MFMA16(a1, c1, c);
      int s0 = nt * 16;
#pragma unroll
      for (int r = 0; r < 4; r++) sc[kg * 4 + r][s0 + lr] = (__bf16)c[r];
      nt += 16;
    }
  }

  // amask prefetch: issue before the barrier so it fills during the sync.
  f32x4 ab[4];
#pragma unroll
  for (int i = 0; i < 4; i++) ab[i] = *(const f32x4*)&am[lane * 4 + 256 * i];
  __syncthreads();

  // Phase B: single streaming pass over row m, rpos+amask both 4-deep.
  float sum = 0.f;
  bf16x4 ereg[8];
  {
#pragma unroll
    for (int i = 0; i < 8; i++) {
      int c = lane * 4 + 256 * i;
      f32x4 r4 = rb[i & 3];
      f32x4 a4 = ab[i & 3];
      if (i < 4) {
        rb[i] = __builtin_nontemporal_load((const f32x4*)&rp[c + 1024]);
        ab[i] = *(const f32x4*)&am[c + 1024];
      }
      bf16x4 sv = *(const bf16x4*)&sc[m][c];
      f32x4 b4 = *(const f32x4*)&bias[c];
      f32x4 e4;
      e4[0] = __expf((float)sv[0] + a4[0] + r4[0] + b4[0]);
      e4[1] = __expf((float)sv[1] + a4[1] + r4[1] + b4[1]);
      e4[2] = __expf((float)sv[2] + a4[2] + r4[2] + b4[2]);
      e4[3] = __expf((float)sv[3] + a4[3] + r4[3] + b4[3]);
      bf16x4 ev;
      ev[0] = (__bf16)e4[0]; ev[1] = (__bf16)e4[1];
      ev[2] = (__bf16)e4[2]; ev[3] = (__bf16)e4[3];
      ereg[i] = ev;
      *(bf16x4*)&sc[m][c] = ev;
      sum += e4[0] + e4[1] + e4[2] + e4[3];
    }
#pragma unroll
    for (int o = 32; o >= 1; o >>= 1) sum += __shfl_xor(sum, o);
    if (lane == 0) invA[m] = 1.0f / sum;
  }
  __syncthreads();

  // wout stores (nontemporal, fire-and-forget; overlap PV below).
  {
    float inv = 1.0f / sum;
    float* wr = wout + ((size_t)(h * 2 + b) * 2048 + t) * 2048;
#pragma unroll
    for (int i = 0; i < 8; i++) {
      int c = lane * 4 + 256 * i;
      bf16x4 ev = ereg[i];
      f32x4 w4;
      w4[0] = (float)ev[0] * inv; w4[1] = (float)ev[1] * inv;
      w4[2] = (float)ev[2] * inv; w4[3] = (float)ev[3] * inv;
      __builtin_nontemporal_store(w4, (f32x4*)&wr[c]);
    }
  }

  // Phase C: PV, 2-deep prefetch of vT fragment + LDS A-fragment.
  f32x4 acc = (f32x4){0.f, 0.f, 0.f, 0.f};
  {
    int jt = wv & 3, kc = wv >> 2;
    const __bf16* vb = vp + (size_t)(jt * 16 + lr) * 2048 + kc * 16 * 32 + kg * 8;
    const __bf16* ab0 = &sc[lr][kc * 16 * 32 + kg * 8];
    bf16x8 nb = *(const bf16x8*)vb;
    bf16x8 na = *(const bf16x8*)ab0;
#pragma unroll
    for (int it = 0; it < 16; it++) {
      bf16x8 bv = nb, av = na;
      if (it < 15) {
        nb = *(const bf16x8*)(vb + (it + 1) * 32);
        na = *(const bf16x8*)(ab0 + (it + 1) * 32);
      }
      __builtin_amdgcn_sched_barrier(0);  // pin prefetch issue before MFMA
      acc = MFMA16(av, bv, acc);
    }
  }
  __syncthreads();  // all sc reads complete; overlay pl
  {
    int jt = wv & 3, kc = wv >> 2;
#pragma unroll
    for (int r = 0; r < 4; r++) pl[kc][jt][kg * 4 + r][lr] = acc[r];
  }
  __syncthreads();
  {
    int row = threadIdx.x >> 6;
    int cc = threadIdx.x & 63;
    int jj = cc >> 4, col = cc & 15;
    float s = (pl[0][jj][row][col] + pl[1][jj][row][col] +
               pl[2][jj][row][col] + pl[3][jj][row][col]) * invA[row];
    attn_pre[((size_t)b * 2048 + t0 + row) * 768 + h * 64 + cc] = s;
  }
}

// ---------------------------------------------------------------------------
// K3: LayerNorm over last dim (768), output bf16. One wave per row.
// ---------------------------------------------------------------------------
__global__ __launch_bounds__(256) void ln_kernel(
    const float* __restrict__ x, const float* __restrict__ g,
    const float* __restrict__ be, __bf16* __restrict__ out) {
  int row = blockIdx.x * 4 + (threadIdx.x >> 6);
  int lane = threadIdx.x & 63;
  const float* xr = x + (size_t)row * 768;
  float v[12];
  float s = 0.f;
#pragma unroll
  for (int i = 0; i < 12; i++) {
    v[i] = xr[lane + 64 * i];
    s += v[i];
  }
#pragma unroll
  for (int o = 32; o >= 1; o >>= 1) s += __shfl_xor(s, o);
  float mu = s * (1.0f / 768.0f);
  float var = 0.f;
#pragma unroll
  for (int i = 0; i < 12; i++) {
    float d = v[i] - mu;
    var += d * d;
  }
#pragma unroll
  for (int o = 32; o >= 1; o >>= 1) var += __shfl_xor(var, o);
  var *= (1.0f / 768.0f);
  float rs = rsqrtf(var + 1e-5f);
#pragma unroll
  for (int i = 0; i < 12; i++) {
    int c = lane + 64 * i;
    out[(size_t)row * 768 + c] = (__bf16)((v[i] - mu) * rs * g[c] + be[c]);
  }
}

// ---------------------------------------------------------------------------
// K4: output projection, 4-way split-K per block, bf16 Wo. grid 768.
// ---------------------------------------------------------------------------
__global__ __launch_bounds__(256) void oproj_kernel(
    const __bf16* __restrict__ Xb, const __bf16* __restrict__ W,
    const float* __restrict__ bias, float* __restrict__ out) {
  __shared__ float pl[4][64][65];
  int wv = threadIdx.x >> 6;
  int lane = threadIdx.x & 63;
  int lr = lane & 15, kg = lane >> 4;
  int tile = blockIdx.x;
  int mt = tile / 12, nt = tile - mt * 12;
  int m0 = mt * 64, n0 = nt * 64;
  f32x4 acc[4][4];
#pragma unroll
  for (int i = 0; i < 4; i++)
#pragma unroll
    for (int j = 0; j < 4; j++) acc[i][j] = (f32x4){0.f, 0.f, 0.f, 0.f};

  int k0b = wv * 192;
  for (int k0 = k0b; k0 < k0b + 192; k0 += 32) {
    bf16x8 af[4], bw[4];
#pragma unroll
    for (int i = 0; i < 4; i++) {
      af[i] = *(const bf16x8*)(Xb + (size_t)(m0 + i * 16 + lr) * 768 + k0 + kg * 8);
      bw[i] = *(const bf16x8*)(W + (size_t)(n0 + i * 16 + lr) * 768 + k0 + kg * 8);
    }
#pragma unroll
    for (int i = 0; i < 4; i++)
#pragma unroll
      for (int j = 0; j < 4; j++) acc[i][j] = MFMA16(af[i], bw[j], acc[i][j]);
  }

#pragma unroll
  for (int i = 0; i < 4; i++)
#pragma unroll
    for (int j = 0; j < 4; j++)
#pragma unroll
      for (int r = 0; r < 4; r++)
        pl[wv][i * 16 + kg * 4 + r][j * 16 + lr] = acc[i][j][r];
  __syncthreads();
#pragma unroll
  for (int e = 0; e < 16; e++) {
    int idx = threadIdx.x + e * 256;
    int mm = idx >> 6, nn = idx & 63;
    float s = pl[0][mm][nn] + pl[1][mm][nn] + pl[2][mm][nn] + pl[3][mm][nn];
    out[(size_t)(m0 + mm) * 768 + n0 + nn] = s + bias[n0 + nn];
  }
}

extern "C" void kernel_launch(void* const* d_in, const int* in_sizes, int n_in,
                              void* d_out, int out_size, void* d_ws, size_t ws_size,
                              hipStream_t stream) {
  const float* query = (const float*)d_in[0];
  const float* key = (const float*)d_in[1];
  const float* value = (const float*)d_in[2];
  const int* kpm = (const int*)d_in[3];
  const float* amask = (const float*)d_in[4];
  const float* rpos = (const float*)d_in[5];
  const float* Wq = (const float*)d_in[6];
  const float* bq = (const float*)d_in[7];
  const float* Wk = (const float*)d_in[8];
  const float* bk = (const float*)d_in[9];
  const float* Wv = (const float*)d_in[10];
  const float* bv = (const float*)d_in[11];
  const float* Wo = (const float*)d_in[12];
  const float* bo = (const float*)d_in[13];
  const float* lng = (const float*)d_in[14];
  const float* lnb = (const float*)d_in[15];

  char* ws = (char*)d_ws;
  __bf16* qw = (__bf16*)ws;                    // 6,291,456
  __bf16* kw = (__bf16*)(ws + 6291456);        // 6,291,456
  __bf16* vT = (__bf16*)(ws + 12582912);       // 6,291,456
  float* attn_pre = (float*)(ws + 18874368);   // 12,582,912
  __bf16* lnx = (__bf16*)(ws + 31457280);      // 6,291,456
  __bf16* xqb = (__bf16*)(ws + 37748736);      // 6,291,456
  __bf16* xkb = (__bf16*)(ws + 44040192);      // 6,291,456
  __bf16* xvb = (__bf16*)(ws + 50331648);      // 6,291,456
  __bf16* wqb = (__bf16*)(ws + 56623104);      // 1,179,648
  __bf16* wkb = (__bf16*)(ws + 57802752);      // 1,179,648
  __bf16* wvb = (__bf16*)(ws + 58982400);      // 1,179,648
  __bf16* wob = (__bf16*)(ws + 60162048);      // 1,179,648

  float* out_attn = (float*)d_out;             // [2][2048][768]
  float* out_w = out_attn + 3145728;           // [12][2][2048][2048]

  cast_kernel<<<11520, dim3(256), 0, stream>>>(query, key, value, Wq, Wk, Wv,
                                               Wo, xqb, xkb, xvb, wqb, wkb,
                                               wvb, wob);
  qkv_kernel<<<2304, dim3(64), 0, stream>>>(xqb, xkb, xvb, wqb, wkb, wvb,
                                            bq, bk, bv, qw, kw, vT);
  attn_kernel<<<3072, dim3(1024), 0, stream>>>(qw, kw, vT, kpm, amask, rpos,
                                               out_w, attn_pre);
  ln_kernel<<<1024, dim3(256), 0, stream>>>(attn_pre, lng, lnb, lnx);
  oproj_kernel<<<768, dim3(256), 0, stream>>>(lnx, wob, bo, out_attn);
}

// Round 17
// 379.010 us; speedup vs baseline: 1.0140x; 1.0140x over previous
//
#include <hip/hip_runtime.h>
#include <hip/hip_bf16.h>

typedef __attribute__((ext_vector_type(8))) __bf16 bf16x8;
typedef __attribute__((ext_vector_type(4))) __bf16 bf16x4;
typedef __attribute__((ext_vector_type(4))) float f32x4;

#define MFMA16(a, b, c) __builtin_amdgcn_mfma_f32_16x16x32_bf16((a), (b), (c), 0, 0, 0)

// ---------------------------------------------------------------------------
// K0: cast f32 -> bf16 (X3 and W4).
// ---------------------------------------------------------------------------
__global__ __launch_bounds__(256) void cast_kernel(
    const float* __restrict__ xq, const float* __restrict__ xk,
    const float* __restrict__ xv, const float* __restrict__ Wq,
    const float* __restrict__ Wk, const float* __restrict__ Wv,
    const float* __restrict__ Wo, __bf16* __restrict__ oxq,
    __bf16* __restrict__ oxk, __bf16* __restrict__ oxv,
    __bf16* __restrict__ owq, __bf16* __restrict__ owk,
    __bf16* __restrict__ owv, __bf16* __restrict__ owo) {
  int bid = blockIdx.x;
  const float* src;
  __bf16* dst;
  int base;
  if (bid < 3072) { src = xq; dst = oxq; base = bid; }
  else if (bid < 6144) { src = xk; dst = oxk; base = bid - 3072; }
  else if (bid < 9216) { src = xv; dst = oxv; base = bid - 6144; }
  else if (bid < 9792) { src = Wq; dst = owq; base = bid - 9216; }
  else if (bid < 10368) { src = Wk; dst = owk; base = bid - 9792; }
  else if (bid < 10944) { src = Wv; dst = owv; base = bid - 10368; }
  else { src = Wo; dst = owo; base = bid - 10944; }
  int idx = base * 256 + threadIdx.x;
  f32x4 v = *(const f32x4*)&src[idx * 4];
  bf16x4 o;
  o[0] = (__bf16)v[0]; o[1] = (__bf16)v[1]; o[2] = (__bf16)v[2]; o[3] = (__bf16)v[3];
  *(bf16x4*)&dst[idx * 4] = o;
}

// ---------------------------------------------------------------------------
// K1: QKV projection, bf16 inputs, 1 wave per 64x64 tile, grid 2304.
// p<2: out[(b*12+h)*2048+pos][hd];  p==2: out[(b*12+h)*64+hd][pos] (v^T)
// ---------------------------------------------------------------------------
__global__ __launch_bounds__(64) void qkv_kernel(
    const __bf16* __restrict__ xq, const __bf16* __restrict__ xk,
    const __bf16* __restrict__ xv, const __bf16* __restrict__ wq,
    const __bf16* __restrict__ wk, const __bf16* __restrict__ wvp,
    const float* __restrict__ bq, const float* __restrict__ bk,
    const float* __restrict__ bv, __bf16* __restrict__ qo,
    __bf16* __restrict__ ko, __bf16* __restrict__ vo) {
  int wg = blockIdx.x;
  int p = wg / 768;
  int wgi = wg - p * 768;
  const __bf16* X = (p == 0) ? xq : (p == 1) ? xk : xv;
  const __bf16* W = (p == 0) ? wq : (p == 1) ? wk : wvp;
  const float* bias = (p == 0) ? bq : (p == 1) ? bk : bv;
  __bf16* out = (p == 0) ? qo : (p == 1) ? ko : vo;
  float scale = (p == 0) ? 0.125f : 1.0f;
  int vmode = (p == 2);

  int lane = threadIdx.x & 63;
  int lr = lane & 15, kg = lane >> 4;
  int mt = wgi / 12, nt = wgi - mt * 12;
  int m0 = mt * 64, n0 = nt * 64;
  f32x4 acc[4][4];
#pragma unroll
  for (int i = 0; i < 4; i++)
#pragma unroll
    for (int j = 0; j < 4; j++) acc[i][j] = (f32x4){0.f, 0.f, 0.f, 0.f};

  for (int k0 = 0; k0 < 768; k0 += 32) {
    bf16x8 af[4], bw[4];
#pragma unroll
    for (int i = 0; i < 4; i++) {
      af[i] = *(const bf16x8*)(X + (size_t)(m0 + i * 16 + lr) * 768 + k0 + kg * 8);
      bw[i] = *(const bf16x8*)(W + (size_t)(n0 + i * 16 + lr) * 768 + k0 + kg * 8);
    }
#pragma unroll
    for (int i = 0; i < 4; i++)
#pragma unroll
      for (int j = 0; j < 4; j++) acc[i][j] = MFMA16(af[i], bw[j], acc[i][j]);
  }

  int h = nt;
#pragma unroll
  for (int i = 0; i < 4; i++)
#pragma unroll
    for (int j = 0; j < 4; j++)
#pragma unroll
      for (int r = 0; r < 4; r++) {
        int m = m0 + i * 16 + kg * 4 + r;
        int hd = j * 16 + lr;
        float v = (acc[i][j][r] + bias[n0 + hd]) * scale;
        int b = m >> 11, pos = m & 2047;
        size_t idx;
        if (!vmode)
          idx = ((size_t)(b * 12 + h) * 2048 + pos) * 64 + hd;
        else
          idx = ((size_t)(b * 12 + h) * 64 + hd) * 2048 + pos;
        out[idx] = (__bf16)v;
      }
}

// ---------------------------------------------------------------------------
// K2: fused attention (r15 structure — best measured: attn 292us).
// Per (b, h, 16-row q-tile). 1024 threads = 16 waves. LDS ~74KB -> 2 blk/CU.
// rpos (402MB, zero-reuse) loaded nontemporal; wout (402MB, zero-reuse)
// stored nontemporal -> no L2/L3 allocation, preserves K/V/amask residency.
// ---------------------------------------------------------------------------
__global__ __launch_bounds__(1024, 8) void attn_kernel(
    const __bf16* __restrict__ qw, const __bf16* __restrict__ kw,
    const __bf16* __restrict__ vT, const int* __restrict__ kpm,
    const float* __restrict__ amask, const float* __restrict__ rpos,
    float* __restrict__ wout, float* __restrict__ attn_pre) {
  __shared__ __align__(16) unsigned char smem[16 * 2056 * 2];  // sc / pl union
  __shared__ __align__(16) float bias[2048];
  __shared__ float invA[16];
  auto sc = (__bf16(*)[2056])smem;
  auto pl = (float(*)[4][16][16])smem;  // 16KB, overlaid after all sc reads

  int wg = blockIdx.x;
  int qt = wg & 127, bh = wg >> 7;  // 128 q-tiles of 16 rows, bh = b*12+h
  int b = bh / 12, h = bh - b * 12;
  int t0 = qt * 16;
  int wv = threadIdx.x >> 6, lane = threadIdx.x & 63;
  int lr = lane & 15, kg = lane >> 4;

  const __bf16* qp = qw + (size_t)bh * 2048 * 64;
  const __bf16* kp = kw + (size_t)bh * 2048 * 64;
  const __bf16* vp = vT + (size_t)bh * 64 * 2048;

  int m = wv;        // phase-B row owned by this wave
  int t = t0 + m;
  const float* rp = rpos + ((size_t)bh * 2048 + t) * 2048;
  const float* am = amask + (size_t)t * 2048;

  // kpm -> additive bias in LDS (depends only on b)
  {
    int i0 = threadIdx.x * 2;
    int2 kk = *(const int2*)&kpm[b * 2048 + i0];
    bias[i0] = kk.x ? -__builtin_inff() : 0.0f;
    bias[i0 + 1] = kk.y ? -__builtin_inff() : 0.0f;
  }

  // rpos prefetch (nontemporal): first 4 f32x4, hidden under Phase A.
  f32x4 rb[4];
#pragma unroll
  for (int i = 0; i < 4; i++)
    rb[i] = __builtin_nontemporal_load((const f32x4*)&rp[lane * 4 + 256 * i]);

  // Phase A: scores [16][2048] -> bf16 LDS; 2-deep K prefetch pipeline.
  bf16x8 a0 = *(const bf16x8*)(qp + (size_t)(t0 + lr) * 64 + kg * 8);
  bf16x8 a1 = *(const bf16x8*)(qp + (size_t)(t0 + lr) * 64 + 32 + kg * 8);
  {
    int nt = wv;
    const __bf16* kb = kp + (size_t)(nt * 16 + lr) * 64 + kg * 8;
    bf16x8 b0 = *(const bf16x8*)kb;
    bf16x8 b1 = *(const bf16x8*)(kb + 32);
#pragma unroll
    for (int it = 0; it < 8; it++) {
      bf16x8 c0 = b0, c1 = b1;
      if (it < 7) {
        const __bf16* kn = kp + (size_t)((nt + 16) * 16 + lr) * 64 + kg * 8;
        b0 = *(const bf16x8*)kn;
        b1 = *(const bf16x8*)(kn + 32);
      }
      __builtin_amdgcn_sched_barrier(0);  // pin prefetch issue before MFMA
      f32x4 c = (f32x4){0.f, 0.f, 0.f, 0.f};
      c = MFMA16(a0, c0, c);
      c = MFMA16(a1, c1, c);
      int s0 = nt * 16;
#pragma unroll
      for (int r = 0; r < 4; r++) sc[kg * 4 + r][s0 + lr] = (__bf16)c[r];
      nt += 16;
    }
  }

  // amask prefetch: issue before the barrier so it fills during the sync.
  f32x4 ab[4];
#pragma unroll
  for (int i = 0; i < 4; i++) ab[i] = *(const f32x4*)&am[lane * 4 + 256 * i];
  __syncthreads();

  // Phase B: single streaming pass over row m, rpos+amask both 4-deep.
  float sum = 0.f;
  bf16x4 ereg[8];
  {
#pragma unroll
    for (int i = 0; i < 8; i++) {
      int c = lane * 4 + 256 * i;
      f32x4 r4 = rb[i & 3];
      f32x4 a4 = ab[i & 3];
      if (i < 4) {
        rb[i] = __builtin_nontemporal_load((const f32x4*)&rp[c + 1024]);
        ab[i] = *(const f32x4*)&am[c + 1024];
      }
      bf16x4 sv = *(const bf16x4*)&sc[m][c];
      f32x4 b4 = *(const f32x4*)&bias[c];
      f32x4 e4;
      e4[0] = __expf((float)sv[0] + a4[0] + r4[0] + b4[0]);
      e4[1] = __expf((float)sv[1] + a4[1] + r4[1] + b4[1]);
      e4[2] = __expf((float)sv[2] + a4[2] + r4[2] + b4[2]);
      e4[3] = __expf((float)sv[3] + a4[3] + r4[3] + b4[3]);
      bf16x4 ev;
      ev[0] = (__bf16)e4[0]; ev[1] = (__bf16)e4[1];
      ev[2] = (__bf16)e4[2]; ev[3] = (__bf16)e4[3];
      ereg[i] = ev;
      *(bf16x4*)&sc[m][c] = ev;
      sum += e4[0] + e4[1] + e4[2] + e4[3];
    }
#pragma unroll
    for (int o = 32; o >= 1; o >>= 1) sum += __shfl_xor(sum, o);
    if (lane == 0) invA[m] = 1.0f / sum;
  }
  __syncthreads();

  // wout stores (nontemporal, fire-and-forget; overlap PV below).
  {
    float inv = 1.0f / sum;
    float* wr = wout + ((size_t)(h * 2 + b) * 2048 + t) * 2048;
#pragma unroll
    for (int i = 0; i < 8; i++) {
      int c = lane * 4 + 256 * i;
      bf16x4 ev = ereg[i];
      f32x4 w4;
      w4[0] = (float)ev[0] * inv; w4[1] = (float)ev[1] * inv;
      w4[2] = (float)ev[2] * inv; w4[3] = (float)ev[3] * inv;
      __builtin_nontemporal_store(w4, (f32x4*)&wr[c]);
    }
  }

  // Phase C: PV, 2-deep prefetch of vT fragment + LDS A-fragment.
  f32x4 acc = (f32x4){0.f, 0.f, 0.f, 0.f};
  {
    int jt = wv & 3, kc = wv >> 2;
    const __bf16* vb = vp + (size_t)(jt * 16 + lr) * 2048 + kc * 16 * 32 + kg * 8;
    const __bf16* ab0 = &sc[lr][kc * 16 * 32 + kg * 8];
    bf16x8 nb = *(const bf16x8*)vb;
    bf16x8 na = *(const bf16x8*)ab0;
#pragma unroll
    for (int it = 0; it < 16; it++) {
      bf16x8 bv = nb, av = na;
      if (it < 15) {
        nb = *(const bf16x8*)(vb + (it + 1) * 32);
        na = *(const bf16x8*)(ab0 + (it + 1) * 32);
      }
      __builtin_amdgcn_sched_barrier(0);  // pin prefetch issue before MFMA
      acc = MFMA16(av, bv, acc);
    }
  }
  __syncthreads();  // all sc reads complete; overlay pl
  {
    int jt = wv & 3, kc = wv >> 2;
#pragma unroll
    for (int r = 0; r < 4; r++) pl[kc][jt][kg * 4 + r][lr] = acc[r];
  }
  __syncthreads();
  {
    int row = threadIdx.x >> 6;
    int cc = threadIdx.x & 63;
    int jj = cc >> 4, col = cc & 15;
    float s = (pl[0][jj][row][col] + pl[1][jj][row][col] +
               pl[2][jj][row][col] + pl[3][jj][row][col]) * invA[row];
    attn_pre[((size_t)b * 2048 + t0 + row) * 768 + h * 64 + cc] = s;
  }
}

// ---------------------------------------------------------------------------
// K3: LayerNorm over last dim (768), output bf16. One wave per row.
// ---------------------------------------------------------------------------
__global__ __launch_bounds__(256) void ln_kernel(
    const float* __restrict__ x, const float* __restrict__ g,
    const float* __restrict__ be, __bf16* __restrict__ out) {
  int row = blockIdx.x * 4 + (threadIdx.x >> 6);
  int lane = threadIdx.x & 63;
  const float* xr = x + (size_t)row * 768;
  float v[12];
  float s = 0.f;
#pragma unroll
  for (int i = 0; i < 12; i++) {
    v[i] = xr[lane + 64 * i];
    s += v[i];
  }
#pragma unroll
  for (int o = 32; o >= 1; o >>= 1) s += __shfl_xor(s, o);
  float mu = s * (1.0f / 768.0f);
  float var = 0.f;
#pragma unroll
  for (int i = 0; i < 12; i++) {
    float d = v[i] - mu;
    var += d * d;
  }
#pragma unroll
  for (int o = 32; o >= 1; o >>= 1) var += __shfl_xor(var, o);
  var *= (1.0f / 768.0f);
  float rs = rsqrtf(var + 1e-5f);
#pragma unroll
  for (int i = 0; i < 12; i++) {
    int c = lane + 64 * i;
    out[(size_t)row * 768 + c] = (__bf16)((v[i] - mu) * rs * g[c] + be[c]);
  }
}

// ---------------------------------------------------------------------------
// K4: output projection, 4-way split-K per block, bf16 Wo. grid 768.
// ---------------------------------------------------------------------------
__global__ __launch_bounds__(256) void oproj_kernel(
    const __bf16* __restrict__ Xb, const __bf16* __restrict__ W,
    const float* __restrict__ bias, float* __restrict__ out) {
  __shared__ float pl[4][64][65];
  int wv = threadIdx.x >> 6;
  int lane = threadIdx.x & 63;
  int lr = lane & 15, kg = lane >> 4;
  int tile = blockIdx.x;
  int mt = tile / 12, nt = tile - mt * 12;
  int m0 = mt * 64, n0 = nt * 64;
  f32x4 acc[4][4];
#pragma unroll
  for (int i = 0; i < 4; i++)
#pragma unroll
    for (int j = 0; j < 4; j++) acc[i][j] = (f32x4){0.f, 0.f, 0.f, 0.f};

  int k0b = wv * 192;
  for (int k0 = k0b; k0 < k0b + 192; k0 += 32) {
    bf16x8 af[4], bw[4];
#pragma unroll
    for (int i = 0; i < 4; i++) {
      af[i] = *(const bf16x8*)(Xb + (size_t)(m0 + i * 16 + lr) * 768 + k0 + kg * 8);
      bw[i] = *(const bf16x8*)(W + (size_t)(n0 + i * 16 + lr) * 768 + k0 + kg * 8);
    }
#pragma unroll
    for (int i = 0; i < 4; i++)
#pragma unroll
      for (int j = 0; j < 4; j++) acc[i][j] = MFMA16(af[i], bw[j], acc[i][j]);
  }

#pragma unroll
  for (int i = 0; i < 4; i++)
#pragma unroll
    for (int j = 0; j < 4; j++)
#pragma unroll
      for (int r = 0; r < 4; r++)
        pl[wv][i * 16 + kg * 4 + r][j * 16 + lr] = acc[i][j][r];
  __syncthreads();
#pragma unroll
  for (int e = 0; e < 16; e++) {
    int idx = threadIdx.x + e * 256;
    int mm = idx >> 6, nn = idx & 63;
    float s = pl[0][mm][nn] + pl[1][mm][nn] + pl[2][mm][nn] + pl[3][mm][nn];
    out[(size_t)(m0 + mm) * 768 + n0 + nn] = s + bias[n0 + nn];
  }
}

extern "C" void kernel_launch(void* const* d_in, const int* in_sizes, int n_in,
                              void* d_out, int out_size, void* d_ws, size_t ws_size,
                              hipStream_t stream) {
  const float* query = (const float*)d_in[0];
  const float* key = (const float*)d_in[1];
  const float* value = (const float*)d_in[2];
  const int* kpm = (const int*)d_in[3];
  const float* amask = (const float*)d_in[4];
  const float* rpos = (const float*)d_in[5];
  const float* Wq = (const float*)d_in[6];
  const float* bq = (const float*)d_in[7];
  const float* Wk = (const float*)d_in[8];
  const float* bk = (const float*)d_in[9];
  const float* Wv = (const float*)d_in[10];
  const float* bv = (const float*)d_in[11];
  const float* Wo = (const float*)d_in[12];
  const float* bo = (const float*)d_in[13];
  const float* lng = (const float*)d_in[14];
  const float* lnb = (const float*)d_in[15];

  char* ws = (char*)d_ws;
  __bf16* qw = (__bf16*)ws;                    // 6,291,456
  __bf16* kw = (__bf16*)(ws + 6291456);        // 6,291,456
  __bf16* vT = (__bf16*)(ws + 12582912);       // 6,291,456
  float* attn_pre = (float*)(ws + 18874368);   // 12,582,912
  __bf16* lnx = (__bf16*)(ws + 31457280);      // 6,291,456
  __bf16* xqb = (__bf16*)(ws + 37748736);      // 6,291,456
  __bf16* xkb = (__bf16*)(ws + 44040192);      // 6,291,456
  __bf16* xvb = (__bf16*)(ws + 50331648);      // 6,291,456
  __bf16* wqb = (__bf16*)(ws + 56623104);      // 1,179,648
  __bf16* wkb = (__bf16*)(ws + 57802752);      // 1,179,648
  __bf16* wvb = (__bf16*)(ws + 58982400);      // 1,179,648
  __bf16* wob = (__bf16*)(ws + 60162048);      // 1,179,648

  float* out_attn = (float*)d_out;             // [2][2048][768]
  float* out_w = out_attn + 3145728;           // [12][2][2048][2048]

  cast_kernel<<<11520, dim3(256), 0, stream>>>(query, key, value, Wq, Wk, Wv,
                                               Wo, xqb, xkb, xvb, wqb, wkb,
                                               wvb, wob);
  qkv_kernel<<<2304, dim3(64), 0, stream>>>(xqb, xkb, xvb, wqb, wkb, wvb,
                                            bq, bk, bv, qw, kw, vT);
  attn_kernel<<<3072, dim3(1024), 0, stream>>>(qw, kw, vT, kpm, amask, rpos,
                                               out_w, attn_pre);
  ln_kernel<<<1024, dim3(256), 0, stream>>>(attn_pre, lng, lnb, lnx);
  oproj_kernel<<<768, dim3(256), 0, stream>>>(lnx, wob, bo, out_attn);
}